// Round 8
// baseline (110.908 us; speedup 1.0000x reference)
//
#include <hip/hip_runtime.h>
#include <math.h>

// B=8, L=512, HID=256, LAT=256, INNER=512, NL=3, M=B*L=4096

typedef __attribute__((ext_vector_type(8))) __bf16 bf16x8;
typedef __attribute__((ext_vector_type(4))) float f32x4;

__device__ __forceinline__ unsigned short f2b(float f) {
  unsigned int x = __float_as_uint(f);
  unsigned int r = (x + 0x7fffu + ((x >> 16) & 1u)) >> 16;  // RNE
  return (unsigned short)r;
}

__device__ __forceinline__ void wave_reduce2(float& a, float& b) {
#pragma unroll
  for (int off = 32; off > 0; off >>= 1) {
    a += __shfl_xor(a, off, 64);
    b += __shfl_xor(b, off, 64);
  }
}
__device__ __forceinline__ float wave_reduce1(float a) {
#pragma unroll
  for (int off = 32; off > 0; off >>= 1) a += __shfl_xor(a, off, 64);
  return a;
}

__device__ __forceinline__ bf16x8 cvt8(float4 a, float4 b) {
  bf16x8 r;
  r[0] = (__bf16)a.x; r[1] = (__bf16)a.y; r[2] = (__bf16)a.z; r[3] = (__bf16)a.w;
  r[4] = (__bf16)b.x; r[5] = (__bf16)b.y; r[6] = (__bf16)b.z; r[7] = (__bf16)b.w;
  return r;
}

#define GLD16(gsrc, ldst)                                              \
  __builtin_amdgcn_global_load_lds(                                    \
      (const __attribute__((address_space(1))) void*)(gsrc),           \
      (__attribute__((address_space(3))) void*)(ldst), 16, 0, 0)

// ---------------------------------------------------------------------------
// Setup: z=0..6 weight transpose fp32 [R][C] -> bf16 [C][R].
// ---------------------------------------------------------------------------
__global__ __launch_bounds__(256) void k_setup(
    const float* __restrict__ inproj, const float* __restrict__ binw,
    const float* __restrict__ boutw, unsigned short* __restrict__ inwT,
    unsigned short* __restrict__ binwT, unsigned short* __restrict__ boutwT) {
  __shared__ float t[32][33];
  const int z = blockIdx.z;
  const float* src;
  unsigned short* dst;
  int R, Cc;
  if (z == 0) {
    src = inproj; dst = inwT; R = 256; Cc = 256;
  } else if (z <= 3) {
    src = binw + (size_t)(z - 1) * 256 * 1024;
    dst = binwT + (size_t)(z - 1) * 1024 * 256;
    R = 256; Cc = 1024;
  } else {
    src = boutw + (size_t)(z - 4) * 512 * 256;
    dst = boutwT + (size_t)(z - 4) * 256 * 512;
    R = 512; Cc = 256;
  }
  const int bx = blockIdx.x, by = blockIdx.y;
  if (bx * 32 >= Cc || by * 32 >= R) return;
  const int tx = threadIdx.x & 31, ty = threadIdx.x >> 5;
#pragma unroll
  for (int j = 0; j < 4; ++j)
    t[ty + j * 8][tx] = src[(size_t)(by * 32 + ty + j * 8) * Cc + bx * 32 + tx];
  __syncthreads();
#pragma unroll
  for (int j = 0; j < 4; ++j)
    dst[(size_t)(bx * 32 + ty + j * 8) * R + by * 32 + tx] = f2b(t[tx][ty + j * 8]);
}

// ---------------------------------------------------------------------------
// Fused GEMM + row-norm epilogue. BM=16, BN=256 full row, KTOT in chunks of
// 128 (A-chunk + B-chunk double-buffered, XOR-swizzled slots, prefetch issued
// AFTER the barrier so it overlaps compute).  [round-6 PASSED version, verbatim]
// MODE 0: h = LN1(P); hnb = bf16(LN2(h))   (A = x fp32, GEMM1 + dual LN)
// MODE 1: h += RMS(P)*rw; hnb = bf16(LN(h))
// MODE 2: h += RMS(P)*rw; part[blk] = colsum
// ---------------------------------------------------------------------------
template <int KTOT, int MODE, bool AF32>
__global__ __launch_bounds__(256) void k_gemm_epi(
    const void* __restrict__ A, const unsigned short* __restrict__ Bt,
    const float* __restrict__ p1, const float* __restrict__ p2,
    const float* __restrict__ g2, const float* __restrict__ b2,
    float* __restrict__ h, unsigned short* __restrict__ hnb,
    float* __restrict__ part) {
  constexpr int NCH = KTOT / 128;
  constexpr int ABYTES = AF32 ? 8192 : 4096;  // 16 rows x 128 k
  __shared__ __align__(16) unsigned char smem[2 * ABYTES + 2 * 65536];
  __shared__ float ppart[4][256];
  unsigned char* sAb = smem;                  // [2][ABYTES]
  unsigned char* sBb = smem + 2 * ABYTES;     // [2][64 KB] 256 rows x 128 k
  float* ep = (float*)smem;                   // [16][260] overlay after loop
  const float* Af = (const float*)A;
  const unsigned short* Ab = (const unsigned short*)A;
  const int tid = threadIdx.x;
  const int lane = tid & 63;
  const int wc = tid >> 6;
  const int bm0 = blockIdx.x * 16;
  const int fr = lane & 15, fg = lane >> 4;

  auto stage = [&](int buf, int c) {
    if (AF32) {  // A fp32: 512 slots (row=idx>>5, 32 slots/row)
#pragma unroll
      for (int j = 0; j < 2; ++j) {
        int idx = tid + j * 256;
        int row = idx >> 5, p = idx & 31, l = p ^ (row & 7);
        GLD16(Af + (size_t)(bm0 + row) * KTOT + c * 128 + l * 4,
              sAb + buf * ABYTES + idx * 16);
      }
    } else {  // A bf16: 256 slots (16 slots/row)
      int row = tid >> 4, p = tid & 15, l = p ^ (row & 7);
      GLD16(Ab + (size_t)(bm0 + row) * KTOT + c * 128 + l * 8,
            sAb + buf * ABYTES + tid * 16);
    }
    // B: 4096 slots (256 rows x 16 slots)
#pragma unroll
    for (int j = 0; j < 16; ++j) {
      int idx = tid + j * 256;
      int row = idx >> 4, p = idx & 15, l = p ^ (row & 7);
      GLD16(Bt + (size_t)row * KTOT + c * 128 + l * 8, sBb + buf * 65536 + idx * 16);
    }
  };

  f32x4 acc[4] = {};
  stage(0, 0);
  for (int c = 0; c < NCH; ++c) {
    const int cur = c & 1;
    __syncthreads();                         // drain chunk c, sync compute c-1
    if (c + 1 < NCH) stage(cur ^ 1, c + 1);  // prefetch overlaps compute
#pragma unroll
    for (int kk = 0; kk < 128; kk += 32) {
      bf16x8 af;
      if (AF32) {
        int l0 = (kk >> 2) + fg * 2;
        int p0 = l0 ^ (fr & 7), p1 = (l0 + 1) ^ (fr & 7);
        const float* base = (const float*)(sAb + cur * ABYTES) + fr * 128;
        float4 v0 = *(const float4*)(base + p0 * 4);
        float4 v1 = *(const float4*)(base + p1 * 4);
        af = cvt8(v0, v1);
      } else {
        int p = ((kk >> 3) + fg) ^ (fr & 7);
        af = *(const bf16x8*)((const unsigned short*)(sAb + cur * ABYTES) + fr * 128 +
                              p * 8);
      }
      int pb = ((kk >> 3) + fg) ^ (fr & 7);
#pragma unroll
      for (int n = 0; n < 4; ++n) {
        const unsigned short* bp = (const unsigned short*)(sBb + cur * 65536) +
                                   (wc * 64 + n * 16 + fr) * 128 + pb * 8;
        acc[n] = __builtin_amdgcn_mfma_f32_16x16x32_bf16(af, *(const bf16x8*)bp,
                                                         acc[n], 0, 0, 0);
      }
    }
  }
  __syncthreads();  // all waves done reading sA/sB before ep overlay
#pragma unroll
  for (int n = 0; n < 4; ++n)
#pragma unroll
    for (int j = 0; j < 4; ++j)
      ep[(fg * 4 + j) * 260 + wc * 64 + n * 16 + fr] = acc[n][j];
  __syncthreads();
  // norm phase: wave wc handles rows wc*4..wc*4+3 ; lane covers 4 cols
  const int c0 = lane * 4;
  float4 q1 = *(const float4*)&p1[c0];
  float4 q2v = (MODE == 0) ? *(const float4*)&p2[c0] : float4{0, 0, 0, 0};
  float4 gg2 = (MODE != 2) ? *(const float4*)&g2[c0] : float4{0, 0, 0, 0};
  float4 bb2 = (MODE != 2) ? *(const float4*)&b2[c0] : float4{0, 0, 0, 0};
  float4 psum = {0.f, 0.f, 0.f, 0.f};
#pragma unroll
  for (int r = 0; r < 4; ++r) {
    const int row = wc * 4 + r;
    const size_t grow = (size_t)(bm0 + row) * 256 + c0;
    float4 v = *(const float4*)&ep[row * 260 + c0];
    float4 hh;
    if (MODE == 0) {
      float s = v.x + v.y + v.z + v.w;
      float sq = v.x * v.x + v.y * v.y + v.z * v.z + v.w * v.w;
      wave_reduce2(s, sq);
      float mu = s * (1.f / 256.f);
      float rstd = rsqrtf(sq * (1.f / 256.f) - mu * mu + 1e-5f);
      hh.x = (v.x - mu) * rstd * q1.x + q2v.x;
      hh.y = (v.y - mu) * rstd * q1.y + q2v.y;
      hh.z = (v.z - mu) * rstd * q1.z + q2v.z;
      hh.w = (v.w - mu) * rstd * q1.w + q2v.w;
      *(float4*)&h[grow] = hh;
    } else {
      float sq = v.x * v.x + v.y * v.y + v.z * v.z + v.w * v.w;
      sq = wave_reduce1(sq);
      float rstd = rsqrtf(sq * (1.f / 256.f) + 1e-6f);
      hh = *(const float4*)&h[grow];
      hh.x += v.x * rstd * q1.x;
      hh.y += v.y * rstd * q1.y;
      hh.z += v.z * rstd * q1.z;
      hh.w += v.w * rstd * q1.w;
      *(float4*)&h[grow] = hh;
    }
    if (MODE != 2) {
      float s2 = hh.x + hh.y + hh.z + hh.w;
      float sq2 = hh.x * hh.x + hh.y * hh.y + hh.z * hh.z + hh.w * hh.w;
      wave_reduce2(s2, sq2);
      float mu2 = s2 * (1.f / 256.f);
      float rs2 = rsqrtf(sq2 * (1.f / 256.f) - mu2 * mu2 + 1e-5f);
      ushort4 u;
      u.x = f2b((hh.x - mu2) * rs2 * gg2.x + bb2.x);
      u.y = f2b((hh.y - mu2) * rs2 * gg2.y + bb2.y);
      u.z = f2b((hh.z - mu2) * rs2 * gg2.z + bb2.z);
      u.w = f2b((hh.w - mu2) * rs2 * gg2.w + bb2.w);
      *(ushort4*)&hnb[grow] = u;
    } else {
      psum.x += hh.x;
      psum.y += hh.y;
      psum.z += hh.z;
      psum.w += hh.w;
    }
  }
  if (MODE == 2) {
    *(float4*)&ppart[wc][c0] = psum;
    __syncthreads();
    float pv = ppart[0][tid] + ppart[1][tid] + ppart[2][tid] + ppart[3][tid];
    part[(size_t)blockIdx.x * 256 + tid] = pv;
  }
}

// ---------------------------------------------------------------------------
// Fused GEMM2 + conv3 + decay-scan + gate. Block = (16-ch tile d0, batch b).
// B-slice (u,g weight rows: shared by all waves) staged ONCE in LDS;
// A slab rows (disjoint per wave) streamed per-lane from L2. Flat K-loop.
// [bisect candidate: only change vs the round-6 passed kernel]
// ---------------------------------------------------------------------------
__global__ __launch_bounds__(256) void k_gemm2_scan(
    const unsigned short* __restrict__ A,   // hnb [4096][256]
    const unsigned short* __restrict__ Bt,  // binwT layer base [1024][256]
    const float* __restrict__ cw, const float* __restrict__ decay,
    const float* __restrict__ scl, unsigned short* __restrict__ y) {
  __shared__ __align__(16) unsigned short sB[32 * 256];  // 16 KB, swizzled
  __shared__ float su[16 * 520];                         // 32.5 KB u planes
  __shared__ float sg[16 * 520];                         // 32.5 KB g planes
  __shared__ float lend[16][16];
  __shared__ float carry[16][16];
  const int b = blockIdx.y;
  const int d0 = blockIdx.x * 16;
  const int tid = threadIdx.x;
  const int lane = tid & 63;
  const int w = tid >> 6;
  const int fr = lane & 15, fg = lane >> 4;
  const unsigned short* Abp = A + (size_t)b * 512 * 256;

  // stage B once: 1024 slots x 16 B, 32 slots/row, XOR-swizzled low-3
#pragma unroll
  for (int j = 0; j < 4; ++j) {
    int idx = tid + j * 256;
    int row = idx >> 5, p = idx & 31;
    int l = p ^ (row & 7);
    int gr = row < 16 ? d0 + row : 496 + d0 + row;
    GLD16(Bt + (size_t)gr * 256 + l * 8, (unsigned char*)sB + idx * 16);
  }
  __syncthreads();

  f32x4 au[8] = {}, ag[8] = {};
#pragma unroll 2
  for (int kt = 0; kt < 256; kt += 32) {
    int s = (kt >> 3) + fg;
    int ps = s ^ (fr & 7);
    bf16x8 bu = *(const bf16x8*)&sB[fr * 256 + ps * 8];
    bf16x8 bg = *(const bf16x8*)&sB[(16 + fr) * 256 + ps * 8];
    bf16x8 af[8];
#pragma unroll
    for (int m = 0; m < 8; ++m)
      af[m] = *(const bf16x8*)&Abp[(size_t)(w * 128 + m * 16 + fr) * 256 + kt + fg * 8];
#pragma unroll
    for (int m = 0; m < 8; ++m) {
      au[m] = __builtin_amdgcn_mfma_f32_16x16x32_bf16(af[m], bu, au[m], 0, 0, 0);
      ag[m] = __builtin_amdgcn_mfma_f32_16x16x32_bf16(af[m], bg, ag[m], 0, 0, 0);
    }
  }
  __syncthreads();
  // scatter accumulators -> planes: row = w*128+m*16+fg*4+j, channel fr
#pragma unroll
  for (int m = 0; m < 8; ++m)
#pragma unroll
    for (int j = 0; j < 4; ++j) {
      int row = w * 128 + m * 16 + fg * 4 + j;
      int off = (row >> 5) * 520 + (row & 31) * 16 + fr;
      su[off] = au[m][j];
      sg[off] = ag[m][j];
    }
  __syncthreads();
  // scan: thread = (ds, ch); chunk ch covers t in [ch*32, ch*32+32)
  const int ds = tid & 15, ch = tid >> 4;
  const int d = d0 + ds;
  const float a = 1.f / (1.f + __expf(-decay[d]));
  const float coef = (1.f - a) * scl[d];
  const float cw0 = cw[d * 3], cw1 = cw[d * 3 + 1], cw2 = cw[d * 3 + 2];
  const int T0 = ch * 32;
  float um1 = T0 >= 1 ? su[((T0 - 1) >> 5) * 520 + ((T0 - 1) & 31) * 16 + ds] : 0.f;
  float um2 = T0 >= 2 ? su[((T0 - 2) >> 5) * 520 + ((T0 - 2) & 31) * 16 + ds] : 0.f;
  float s = 0.f, s0r[32];
#pragma unroll
  for (int t = 0; t < 32; ++t) {
    float u = su[ch * 520 + t * 16 + ds];
    float uc = fmaf(cw0, um2, fmaf(cw1, um1, cw2 * u));
    s = fmaf(a, s, coef * uc);
    s0r[t] = s;
    um2 = um1;
    um1 = u;
  }
  lend[ch][ds] = s;
  __syncthreads();
  if (tid < 16) {
    float aa = 1.f / (1.f + __expf(-decay[d0 + tid]));
    float a32 = aa * aa;
    a32 = a32 * a32;
    a32 = a32 * a32;
    a32 = a32 * a32;
    a32 = a32 * a32;  // a^32
    float c = 0.f;
#pragma unroll
    for (int j = 0; j < 16; ++j) {
      carry[j][tid] = c;
      c = fmaf(a32, c, lend[j][tid]);
    }
  }
  __syncthreads();
  const float c = carry[ch][ds];
  unsigned short* yp = y + ((size_t)b * 512 + T0) * 512 + d;
  float ap = a;
#pragma unroll
  for (int t = 0; t < 32; ++t) {
    float gv = sg[ch * 520 + t * 16 + ds];
    float sv = fmaf(ap, c, s0r[t]);
    float sig = 1.f / (1.f + __expf(-gv));
    yp[(size_t)t * 512] = f2b(sv * sig);
    ap *= a;
  }
}

// ---------------------------------------------------------------------------
// Fused head: pool-finish -> GEMV1 -> LN -> GELU -> GEMV2. 8 blocks x (256,4).
// part layout: [256 blocks][256 cols]; batch b owns blocks b*32..b*32+31.
// ---------------------------------------------------------------------------
__global__ __launch_bounds__(1024) void k_head(
    const float* __restrict__ part, const float* __restrict__ h,
    const float* __restrict__ w1, const float* __restrict__ b1,
    const float* __restrict__ lng, const float* __restrict__ lnb,
    const float* __restrict__ w2, const float* __restrict__ b2,
    float* __restrict__ out) {
  const int b = blockIdx.x;
  const int t = threadIdx.x;
  const int ks = threadIdx.y;
  __shared__ float sp[256];
  __shared__ float sz[256];
  __shared__ float part4[4][256];
  __shared__ float red[8];
  if (ks == 0) {
    float s = 0.f;
#pragma unroll
    for (int j = 0; j < 32; ++j) s += part[((size_t)b * 32 + j) * 256 + t];
    sp[t] = s * (0.5f / 512.f) + 0.5f * h[(((size_t)b * 512) + 511) * 256 + t];
  }
  __syncthreads();
  float acc = 0.f;
#pragma unroll 8
  for (int k = ks * 64; k < ks * 64 + 64; ++k) acc += sp[k] * w1[(size_t)k * 256 + t];
  part4[ks][t] = acc;
  __syncthreads();
  if (ks == 0) {
    float aval = part4[0][t] + part4[1][t] + part4[2][t] + part4[3][t] + b1[t];
    float s = aval, sq = aval * aval;
    wave_reduce2(s, sq);
    const int lane = t & 63, w = t >> 6;
    if (lane == 0) {
      red[w] = s;
      red[4 + w] = sq;
    }
    part4[0][t] = aval;  // stash
  }
  __syncthreads();
  if (ks == 0) {
    float S = red[0] + red[1] + red[2] + red[3];
    float SQ = red[4] + red[5] + red[6] + red[7];
    float mu = S * (1.f / 256.f);
    float rstd = rsqrtf(SQ * (1.f / 256.f) - mu * mu + 1e-5f);
    float zv = (part4[0][t] - mu) * rstd * lng[t] + lnb[t];
    zv = 0.5f * zv * (1.f + erff(zv * 0.70710678118654752f));
    sz[t] = zv;
  }
  __syncthreads();
  const int col = ks * 256 + t;
  if (col < 768) {
    float a = b2[col];
#pragma unroll 8
    for (int k = 0; k < 256; ++k) a += sz[k] * w2[(size_t)k * 768 + col];
    out[(size_t)b * 768 + col] = a;
  }
}

// ---------------------------------------------------------------------------
extern "C" void kernel_launch(void* const* d_in, const int* in_sizes, int n_in,
                              void* d_out, int out_size, void* d_ws, size_t ws_size,
                              hipStream_t stream) {
  const float* x = (const float*)d_in[0];
  const float* in_proj_w = (const float*)d_in[1];
  const float* in_ln_g = (const float*)d_in[2];
  const float* in_ln_b = (const float*)d_in[3];
  const float* norms_g = (const float*)d_in[4];
  const float* norms_b = (const float*)d_in[5];
  const float* blk_in_w = (const float*)d_in[6];
  const float* blk_conv_w = (const float*)d_in[7];
  const float* blk_decay = (const float*)d_in[8];
  const float* blk_scale = (const float*)d_in[9];
  const float* blk_out_w = (const float*)d_in[10];
  const float* blk_rms_w = (const float*)d_in[11];
  const float* head_w1 = (const float*)d_in[12];
  const float* head_b1 = (const float*)d_in[13];
  const float* head_ln_g = (const float*)d_in[14];
  const float* head_ln_b = (const float*)d_in[15];
  const float* head_w2 = (const float*)d_in[16];
  const float* head_b2 = (const float*)d_in[17];

  char* wsb = (char*)d_ws;
  float* h = (float*)(wsb + 0);                                // 4 MB [4096][256]
  float* part = (float*)(wsb + (4 << 20));                     // 256 KB [256][256]
  unsigned short* hnb = (unsigned short*)(wsb + (8 << 20));    // 2 MB bf16
  unsigned short* yb = (unsigned short*)(wsb + (12 << 20));    // 4 MB bf16 [4096][512]
  unsigned short* inwT = (unsigned short*)(wsb + (25 << 20));  // [256][256]
  unsigned short* binwT = inwT + 65536;                        // 3x [1024][256]
  unsigned short* boutwT = binwT + 786432;                     // 3x [256][512]
  float* out = (float*)d_out;

  k_setup<<<dim3(32, 16, 7), 256, 0, stream>>>(in_proj_w, blk_in_w, blk_out_w, inwT,
                                               binwT, boutwT);
  // h = LN1(x @ in_proj_w); hnb = bf16(LN2(h))  (A = x fp32 direct)
  k_gemm_epi<256, 0, true><<<256, 256, 0, stream>>>(
      x, inwT, in_ln_g, in_ln_b, norms_g, norms_b, h, hnb, nullptr);
  for (int i = 0; i < 3; ++i) {
    k_gemm2_scan<<<dim3(32, 8), 256, 0, stream>>>(
        hnb, binwT + (size_t)i * 262144, blk_conv_w + i * 1536, blk_decay + i * 512,
        blk_scale + i * 512, yb);
    if (i < 2)
      k_gemm_epi<512, 1, false><<<256, 256, 0, stream>>>(
          yb, boutwT + (size_t)i * 131072, blk_rms_w + i * 256, nullptr,
          norms_g + (i + 1) * 256, norms_b + (i + 1) * 256, h, hnb, nullptr);
    else
      k_gemm_epi<512, 2, false><<<256, 256, 0, stream>>>(
          yb, boutwT + (size_t)i * 131072, blk_rms_w + i * 256, nullptr, nullptr,
          nullptr, h, nullptr, part);
  }
  k_head<<<8, dim3(256, 4), 0, stream>>>(part, h, head_w1, head_b1, head_ln_g,
                                         head_ln_b, head_w2, head_b2, out);
}

// Round 9
// 101.767 us; speedup vs baseline: 1.0898x; 1.0898x over previous
//
#include <hip/hip_runtime.h>
#include <math.h>

// B=8, L=512, HID=256, LAT=256, INNER=512, NL=3, M=B*L=4096

typedef __attribute__((ext_vector_type(8))) __bf16 bf16x8;
typedef __attribute__((ext_vector_type(4))) float f32x4;

__device__ __forceinline__ unsigned short f2b(float f) {
  unsigned int x = __float_as_uint(f);
  unsigned int r = (x + 0x7fffu + ((x >> 16) & 1u)) >> 16;  // RNE
  return (unsigned short)r;
}

__device__ __forceinline__ void wave_reduce2(float& a, float& b) {
#pragma unroll
  for (int off = 32; off > 0; off >>= 1) {
    a += __shfl_xor(a, off, 64);
    b += __shfl_xor(b, off, 64);
  }
}
__device__ __forceinline__ float wave_reduce1(float a) {
#pragma unroll
  for (int off = 32; off > 0; off >>= 1) a += __shfl_xor(a, off, 64);
  return a;
}

__device__ __forceinline__ bf16x8 cvt8(float4 a, float4 b) {
  bf16x8 r;
  r[0] = (__bf16)a.x; r[1] = (__bf16)a.y; r[2] = (__bf16)a.z; r[3] = (__bf16)a.w;
  r[4] = (__bf16)b.x; r[5] = (__bf16)b.y; r[6] = (__bf16)b.z; r[7] = (__bf16)b.w;
  return r;
}

#define GLD16(gsrc, ldst)                                              \
  __builtin_amdgcn_global_load_lds(                                    \
      (const __attribute__((address_space(1))) void*)(gsrc),           \
      (__attribute__((address_space(3))) void*)(ldst), 16, 0, 0)

// ---------------------------------------------------------------------------
// Setup: z=0..6 weight transpose fp32 [R][C] -> bf16 [C][R].
// ---------------------------------------------------------------------------
__global__ __launch_bounds__(256) void k_setup(
    const float* __restrict__ inproj, const float* __restrict__ binw,
    const float* __restrict__ boutw, unsigned short* __restrict__ inwT,
    unsigned short* __restrict__ binwT, unsigned short* __restrict__ boutwT) {
  __shared__ float t[32][33];
  const int z = blockIdx.z;
  const float* src;
  unsigned short* dst;
  int R, Cc;
  if (z == 0) {
    src = inproj; dst = inwT; R = 256; Cc = 256;
  } else if (z <= 3) {
    src = binw + (size_t)(z - 1) * 256 * 1024;
    dst = binwT + (size_t)(z - 1) * 1024 * 256;
    R = 256; Cc = 1024;
  } else {
    src = boutw + (size_t)(z - 4) * 512 * 256;
    dst = boutwT + (size_t)(z - 4) * 256 * 512;
    R = 512; Cc = 256;
  }
  const int bx = blockIdx.x, by = blockIdx.y;
  if (bx * 32 >= Cc || by * 32 >= R) return;
  const int tx = threadIdx.x & 31, ty = threadIdx.x >> 5;
#pragma unroll
  for (int j = 0; j < 4; ++j)
    t[ty + j * 8][tx] = src[(size_t)(by * 32 + ty + j * 8) * Cc + bx * 32 + tx];
  __syncthreads();
#pragma unroll
  for (int j = 0; j < 4; ++j)
    dst[(size_t)(bx * 32 + ty + j * 8) * R + by * 32 + tx] = f2b(t[tx][ty + j * 8]);
}

// ---------------------------------------------------------------------------
// Fused GEMM + row-norm epilogue. BM=16, BN=256 full row, KTOT in chunks of
// 64 (A-chunk + B-chunk double-buffered, XOR-swizzled slots, prefetch issued
// AFTER the barrier so it overlaps compute). LDS ~72-76 KB -> 2 blocks/CU.
// MODE 0: h = LN1(P); hnb = bf16(LN2(h))   (A = x fp32, GEMM1 + dual LN)
// MODE 1: h += RMS(P)*rw; hnb = bf16(LN(h))
// MODE 2: h += RMS(P)*rw; part[blk] = colsum
// ---------------------------------------------------------------------------
template <int KTOT, int MODE, bool AF32>
__global__ __launch_bounds__(256, 2) void k_gemm_epi(
    const void* __restrict__ A, const unsigned short* __restrict__ Bt,
    const float* __restrict__ p1, const float* __restrict__ p2,
    const float* __restrict__ g2, const float* __restrict__ b2,
    float* __restrict__ h, unsigned short* __restrict__ hnb,
    float* __restrict__ part) {
  constexpr int NCH = KTOT / 64;
  constexpr int ABYTES = AF32 ? 4096 : 2048;  // 16 rows x 64 k
  __shared__ __align__(16) unsigned char smem[2 * ABYTES + 2 * 32768];
  __shared__ float ppart[4][256];
  unsigned char* sAb = smem;                  // [2][ABYTES]
  unsigned char* sBb = smem + 2 * ABYTES;     // [2][32 KB] 256 rows x 64 k
  float* ep = (float*)smem;                   // [16][260] overlay after loop
  const float* Af = (const float*)A;
  const unsigned short* Ab = (const unsigned short*)A;
  const int tid = threadIdx.x;
  const int lane = tid & 63;
  const int wc = tid >> 6;
  const int bm0 = blockIdx.x * 16;
  const int fr = lane & 15, fg = lane >> 4;

  auto stage = [&](int buf, int c) {
    if (AF32) {  // A fp32: 256 slots (16 slots/row of 16 B)
      int row = tid >> 4, p = tid & 15;
      int l = (p & ~7) | ((p & 7) ^ (row & 7));
      GLD16(Af + (size_t)(bm0 + row) * KTOT + c * 64 + l * 4,
            sAb + buf * ABYTES + tid * 16);
    } else {  // A bf16: 128 slots (8 slots/row)
      if (tid < 128) {
        int row = tid >> 3, p = tid & 7, l = p ^ (row & 7);
        GLD16(Ab + (size_t)(bm0 + row) * KTOT + c * 64 + l * 8,
              sAb + buf * ABYTES + tid * 16);
      }
    }
    // B: 2048 slots (256 rows x 8 slots)
#pragma unroll
    for (int j = 0; j < 8; ++j) {
      int idx = tid + j * 256;
      int row = idx >> 3, p = idx & 7, l = p ^ (row & 7);
      GLD16(Bt + (size_t)row * KTOT + c * 64 + l * 8, sBb + buf * 32768 + idx * 16);
    }
  };

  f32x4 acc[4] = {};
  stage(0, 0);
  for (int c = 0; c < NCH; ++c) {
    const int cur = c & 1;
    __syncthreads();                         // drain chunk c, sync compute c-1
    if (c + 1 < NCH) stage(cur ^ 1, c + 1);  // prefetch overlaps compute
#pragma unroll
    for (int kk = 0; kk < 64; kk += 32) {
      bf16x8 af;
      if (AF32) {
        int s0 = (kk >> 2) + fg * 2;
        int p0 = (s0 & ~7) | ((s0 & 7) ^ (fr & 7));
        int s1 = s0 + 1;
        int p1i = (s1 & ~7) | ((s1 & 7) ^ (fr & 7));
        const float* base = (const float*)(sAb + cur * ABYTES) + fr * 64;
        float4 v0 = *(const float4*)(base + p0 * 4);
        float4 v1 = *(const float4*)(base + p1i * 4);
        af = cvt8(v0, v1);
      } else {
        int s = (kk >> 3) + fg;
        int ps = s ^ (fr & 7);
        af = *(const bf16x8*)((const unsigned short*)(sAb + cur * ABYTES) + fr * 64 +
                              ps * 8);
      }
      int sb = (kk >> 3) + fg;
      int pb = sb ^ (fr & 7);
#pragma unroll
      for (int n = 0; n < 4; ++n) {
        const unsigned short* bp = (const unsigned short*)(sBb + cur * 32768) +
                                   (wc * 64 + n * 16 + fr) * 64 + pb * 8;
        acc[n] = __builtin_amdgcn_mfma_f32_16x16x32_bf16(af, *(const bf16x8*)bp,
                                                         acc[n], 0, 0, 0);
      }
    }
  }
  __syncthreads();  // all waves done reading sA/sB before ep overlay
#pragma unroll
  for (int n = 0; n < 4; ++n)
#pragma unroll
    for (int j = 0; j < 4; ++j)
      ep[(fg * 4 + j) * 260 + wc * 64 + n * 16 + fr] = acc[n][j];
  __syncthreads();
  // norm phase: wave wc handles rows wc*4..wc*4+3 ; lane covers 4 cols
  const int c0 = lane * 4;
  float4 q1 = *(const float4*)&p1[c0];
  float4 q2v = (MODE == 0) ? *(const float4*)&p2[c0] : float4{0, 0, 0, 0};
  float4 gg2 = (MODE != 2) ? *(const float4*)&g2[c0] : float4{0, 0, 0, 0};
  float4 bb2 = (MODE != 2) ? *(const float4*)&b2[c0] : float4{0, 0, 0, 0};
  float4 psum = {0.f, 0.f, 0.f, 0.f};
#pragma unroll
  for (int r = 0; r < 4; ++r) {
    const int row = wc * 4 + r;
    const size_t grow = (size_t)(bm0 + row) * 256 + c0;
    float4 v = *(const float4*)&ep[row * 260 + c0];
    float4 hh;
    if (MODE == 0) {
      float s = v.x + v.y + v.z + v.w;
      float sq = v.x * v.x + v.y * v.y + v.z * v.z + v.w * v.w;
      wave_reduce2(s, sq);
      float mu = s * (1.f / 256.f);
      float rstd = rsqrtf(sq * (1.f / 256.f) - mu * mu + 1e-5f);
      hh.x = (v.x - mu) * rstd * q1.x + q2v.x;
      hh.y = (v.y - mu) * rstd * q1.y + q2v.y;
      hh.z = (v.z - mu) * rstd * q1.z + q2v.z;
      hh.w = (v.w - mu) * rstd * q1.w + q2v.w;
      *(float4*)&h[grow] = hh;
    } else {
      float sq = v.x * v.x + v.y * v.y + v.z * v.z + v.w * v.w;
      sq = wave_reduce1(sq);
      float rstd = rsqrtf(sq * (1.f / 256.f) + 1e-6f);
      hh = *(const float4*)&h[grow];
      hh.x += v.x * rstd * q1.x;
      hh.y += v.y * rstd * q1.y;
      hh.z += v.z * rstd * q1.z;
      hh.w += v.w * rstd * q1.w;
      *(float4*)&h[grow] = hh;
    }
    if (MODE != 2) {
      float s2 = hh.x + hh.y + hh.z + hh.w;
      float sq2 = hh.x * hh.x + hh.y * hh.y + hh.z * hh.z + hh.w * hh.w;
      wave_reduce2(s2, sq2);
      float mu2 = s2 * (1.f / 256.f);
      float rs2 = rsqrtf(sq2 * (1.f / 256.f) - mu2 * mu2 + 1e-5f);
      ushort4 u;
      u.x = f2b((hh.x - mu2) * rs2 * gg2.x + bb2.x);
      u.y = f2b((hh.y - mu2) * rs2 * gg2.y + bb2.y);
      u.z = f2b((hh.z - mu2) * rs2 * gg2.z + bb2.z);
      u.w = f2b((hh.w - mu2) * rs2 * gg2.w + bb2.w);
      *(ushort4*)&hnb[grow] = u;
    } else {
      psum.x += hh.x;
      psum.y += hh.y;
      psum.z += hh.z;
      psum.w += hh.w;
    }
  }
  if (MODE == 2) {
    *(float4*)&ppart[wc][c0] = psum;
    __syncthreads();
    float pv = ppart[0][tid] + ppart[1][tid] + ppart[2][tid] + ppart[3][tid];
    part[(size_t)blockIdx.x * 256 + tid] = pv;
  }
}

// ---------------------------------------------------------------------------
// Fused GEMM2 + conv3 + decay-scan + gate. Block = (16-ch tile d0, batch b).
// B-slice (u,g weight rows, 16 KB) staged once; A (batch slab 512x256) staged
// in four 64 KB k-quarters, double-buffered, prefetch after barrier.
// Scan planes overlay the dead quarter buffers.  [round-6 PASSED version]
// ---------------------------------------------------------------------------
__global__ __launch_bounds__(256) void k_gemm2_scan(
    const unsigned short* __restrict__ A,   // hnb [4096][256]
    const unsigned short* __restrict__ Bt,  // binwT layer base [1024][256]
    const float* __restrict__ cw, const float* __restrict__ decay,
    const float* __restrict__ scl, unsigned short* __restrict__ y) {
  __shared__ __align__(16) unsigned char smem[16384 + 2 * 65536];
  unsigned short* sB = (unsigned short*)smem;  // [32][256] shorts, swizzled
  unsigned char* qb = smem + 16384;            // [2][64 KB]: 512 rows x 64 k
  float* su = (float*)(smem + 16384);          // overlay: 16 planes x 520
  float* sg = su + 8320;
  float* lend = sg + 8320;    // [16][16]
  float* carry = lend + 256;  // [16][16]
  const int b = blockIdx.y;
  const int d0 = blockIdx.x * 16;
  const int tid = threadIdx.x;
  const int lane = tid & 63;
  const int w = tid >> 6;
  const int fr = lane & 15, fg = lane >> 4;
  const unsigned short* Abp = A + (size_t)b * 512 * 256;

  auto stageQ = [&](int buf, int q) {
#pragma unroll
    for (int j = 0; j < 16; ++j) {
      int idx = tid + j * 256;
      int row = idx >> 3, p = idx & 7, l = p ^ (row & 7);
      GLD16(Abp + (size_t)row * 256 + q * 64 + l * 8, qb + buf * 65536 + idx * 16);
    }
  };
  // stage B once (32 rows x 32 slots)
#pragma unroll
  for (int j = 0; j < 4; ++j) {
    int idx = tid + j * 256;
    int row = idx >> 5, p = idx & 31, l = p ^ (row & 7);
    int gr = row < 16 ? d0 + row : 496 + d0 + row;
    GLD16(Bt + (size_t)gr * 256 + l * 8, smem + idx * 16);
  }
  stageQ(0, 0);

  f32x4 au[8] = {}, ag[8] = {};
#pragma unroll
  for (int q = 0; q < 4; ++q) {
    const int cq = q & 1;
    __syncthreads();                   // drain quarter q (+B on q=0)
    if (q < 3) stageQ(cq ^ 1, q + 1);  // prefetch overlaps compute
#pragma unroll
    for (int kk = 0; kk < 64; kk += 32) {
      int lb = q * 8 + (kk >> 3) + fg;
      int pb = lb ^ (fr & 7);
      bf16x8 bu = *(const bf16x8*)&sB[fr * 256 + pb * 8];
      bf16x8 bg = *(const bf16x8*)&sB[(16 + fr) * 256 + pb * 8];
      int pa = ((kk >> 3) + fg) ^ (fr & 7);
#pragma unroll
      for (int m = 0; m < 8; ++m) {
        int row = w * 128 + m * 16 + fr;
        bf16x8 af =
            *(const bf16x8*)((const unsigned short*)(qb + cq * 65536) + row * 64 +
                             pa * 8);
        au[m] = __builtin_amdgcn_mfma_f32_16x16x32_bf16(af, bu, au[m], 0, 0, 0);
        ag[m] = __builtin_amdgcn_mfma_f32_16x16x32_bf16(af, bg, ag[m], 0, 0, 0);
      }
    }
  }
  __syncthreads();  // all qbuf reads done before scan-plane overlay
  // scatter accumulators -> planes: row = w*128+m*16+fg*4+j, channel fr
#pragma unroll
  for (int m = 0; m < 8; ++m)
#pragma unroll
    for (int j = 0; j < 4; ++j) {
      int row = w * 128 + m * 16 + fg * 4 + j;
      int off = (row >> 5) * 520 + (row & 31) * 16 + fr;
      su[off] = au[m][j];
      sg[off] = ag[m][j];
    }
  __syncthreads();
  // scan: thread = (ds, ch); chunk ch covers t in [ch*32, ch*32+32)
  const int ds = tid & 15, ch = tid >> 4;
  const int d = d0 + ds;
  const float a = 1.f / (1.f + __expf(-decay[d]));
  const float coef = (1.f - a) * scl[d];
  const float cw0 = cw[d * 3], cw1 = cw[d * 3 + 1], cw2 = cw[d * 3 + 2];
  const int T0 = ch * 32;
  float um1 = T0 >= 1 ? su[((T0 - 1) >> 5) * 520 + ((T0 - 1) & 31) * 16 + ds] : 0.f;
  float um2 = T0 >= 2 ? su[((T0 - 2) >> 5) * 520 + ((T0 - 2) & 31) * 16 + ds] : 0.f;
  float s = 0.f, s0r[32];
#pragma unroll
  for (int t = 0; t < 32; ++t) {
    float u = su[ch * 520 + t * 16 + ds];
    float uc = fmaf(cw0, um2, fmaf(cw1, um1, cw2 * u));
    s = fmaf(a, s, coef * uc);
    s0r[t] = s;
    um2 = um1;
    um1 = u;
  }
  lend[ch * 16 + ds] = s;
  __syncthreads();
  if (tid < 16) {
    float aa = 1.f / (1.f + __expf(-decay[d0 + tid]));
    float a32 = aa * aa;
    a32 = a32 * a32;
    a32 = a32 * a32;
    a32 = a32 * a32;
    a32 = a32 * a32;  // a^32
    float c = 0.f;
#pragma unroll
    for (int j = 0; j < 16; ++j) {
      carry[j * 16 + tid] = c;
      c = fmaf(a32, c, lend[j * 16 + tid]);
    }
  }
  __syncthreads();
  const float c = carry[ch * 16 + ds];
  unsigned short* yp = y + ((size_t)b * 512 + T0) * 512 + d;
  float ap = a;
#pragma unroll
  for (int t = 0; t < 32; ++t) {
    float gv = sg[ch * 520 + t * 16 + ds];
    float sv = fmaf(ap, c, s0r[t]);
    float sig = 1.f / (1.f + __expf(-gv));
    yp[(size_t)t * 512] = f2b(sv * sig);
    ap *= a;
  }
}

// ---------------------------------------------------------------------------
// Fused head: pool-finish -> GEMV1 -> LN -> GELU -> GEMV2. 8 blocks x (256,4).
// part layout: [256 blocks][256 cols]; batch b owns blocks b*32..b*32+31.
// ---------------------------------------------------------------------------
__global__ __launch_bounds__(1024) void k_head(
    const float* __restrict__ part, const float* __restrict__ h,
    const float* __restrict__ w1, const float* __restrict__ b1,
    const float* __restrict__ lng, const float* __restrict__ lnb,
    const float* __restrict__ w2, const float* __restrict__ b2,
    float* __restrict__ out) {
  const int b = blockIdx.x;
  const int t = threadIdx.x;
  const int ks = threadIdx.y;
  __shared__ float sp[256];
  __shared__ float sz[256];
  __shared__ float part4[4][256];
  __shared__ float red[8];
  if (ks == 0) {
    float s = 0.f;
#pragma unroll
    for (int j = 0; j < 32; ++j) s += part[((size_t)b * 32 + j) * 256 + t];
    sp[t] = s * (0.5f / 512.f) + 0.5f * h[(((size_t)b * 512) + 511) * 256 + t];
  }
  __syncthreads();
  float acc = 0.f;
#pragma unroll 8
  for (int k = ks * 64; k < ks * 64 + 64; ++k) acc += sp[k] * w1[(size_t)k * 256 + t];
  part4[ks][t] = acc;
  __syncthreads();
  if (ks == 0) {
    float aval = part4[0][t] + part4[1][t] + part4[2][t] + part4[3][t] + b1[t];
    float s = aval, sq = aval * aval;
    wave_reduce2(s, sq);
    const int lane = t & 63, w = t >> 6;
    if (lane == 0) {
      red[w] = s;
      red[4 + w] = sq;
    }
    part4[0][t] = aval;  // stash
  }
  __syncthreads();
  if (ks == 0) {
    float S = red[0] + red[1] + red[2] + red[3];
    float SQ = red[4] + red[5] + red[6] + red[7];
    float mu = S * (1.f / 256.f);
    float rstd = rsqrtf(SQ * (1.f / 256.f) - mu * mu + 1e-5f);
    float zv = (part4[0][t] - mu) * rstd * lng[t] + lnb[t];
    zv = 0.5f * zv * (1.f + erff(zv * 0.70710678118654752f));
    sz[t] = zv;
  }
  __syncthreads();
  const int col = ks * 256 + t;
  if (col < 768) {
    float a = b2[col];
#pragma unroll 8
    for (int k = 0; k < 256; ++k) a += sz[k] * w2[(size_t)k * 768 + col];
    out[(size_t)b * 768 + col] = a;
  }
}

// ---------------------------------------------------------------------------
extern "C" void kernel_launch(void* const* d_in, const int* in_sizes, int n_in,
                              void* d_out, int out_size, void* d_ws, size_t ws_size,
                              hipStream_t stream) {
  const float* x = (const float*)d_in[0];
  const float* in_proj_w = (const float*)d_in[1];
  const float* in_ln_g = (const float*)d_in[2];
  const float* in_ln_b = (const float*)d_in[3];
  const float* norms_g = (const float*)d_in[4];
  const float* norms_b = (const float*)d_in[5];
  const float* blk_in_w = (const float*)d_in[6];
  const float* blk_conv_w = (const float*)d_in[7];
  const float* blk_decay = (const float*)d_in[8];
  const float* blk_scale = (const float*)d_in[9];
  const float* blk_out_w = (const float*)d_in[10];
  const float* blk_rms_w = (const float*)d_in[11];
  const float* head_w1 = (const float*)d_in[12];
  const float* head_b1 = (const float*)d_in[13];
  const float* head_ln_g = (const float*)d_in[14];
  const float* head_ln_b = (const float*)d_in[15];
  const float* head_w2 = (const float*)d_in[16];
  const float* head_b2 = (const float*)d_in[17];

  char* wsb = (char*)d_ws;
  float* h = (float*)(wsb + 0);                                // 4 MB [4096][256]
  float* part = (float*)(wsb + (4 << 20));                     // 256 KB [256][256]
  unsigned short* hnb = (unsigned short*)(wsb + (8 << 20));    // 2 MB bf16
  unsigned short* yb = (unsigned short*)(wsb + (12 << 20));    // 4 MB bf16 [4096][512]
  unsigned short* inwT = (unsigned short*)(wsb + (25 << 20));  // [256][256]
  unsigned short* binwT = inwT + 65536;                        // 3x [1024][256]
  unsigned short* boutwT = binwT + 786432;                     // 3x [256][512]
  float* out = (float*)d_out;

  k_setup<<<dim3(32, 16, 7), 256, 0, stream>>>(in_proj_w, blk_in_w, blk_out_w, inwT,
                                               binwT, boutwT);
  // h = LN1(x @ in_proj_w); hnb = bf16(LN2(h))  (A = x fp32 direct)
  k_gemm_epi<256, 0, true><<<256, 256, 0, stream>>>(
      x, inwT, in_ln_g, in_ln_b, norms_g, norms_b, h, hnb, nullptr);
  for (int i = 0; i < 3; ++i) {
    k_gemm2_scan<<<dim3(32, 8), 256, 0, stream>>>(
        hnb, binwT + (size_t)i * 262144, blk_conv_w + i * 1536, blk_decay + i * 512,
        blk_scale + i * 512, yb);
    if (i < 2)
      k_gemm_epi<512, 1, false><<<256, 256, 0, stream>>>(
          yb, boutwT + (size_t)i * 131072, blk_rms_w + i * 256, nullptr,
          norms_g + (i + 1) * 256, norms_b + (i + 1) * 256, h, hnb, nullptr);
    else
      k_gemm_epi<512, 2, false><<<256, 256, 0, stream>>>(
          yb, boutwT + (size_t)i * 131072, blk_rms_w + i * 256, nullptr, nullptr,
          nullptr, h, nullptr, part);
  }
  k_head<<<8, dim3(256, 4), 0, stream>>>(part, h, head_w1, head_b1, head_ln_g,
                                         head_ln_b, head_w2, head_b2, out);
}